// Round 6
// baseline (287.281 us; speedup 1.0000x reference)
//
#include <hip/hip_runtime.h>
#include <hip/hip_bf16.h>

using bf16 = __hip_bfloat16;

typedef __attribute__((ext_vector_type(8))) __bf16 bf16x8;
typedef __attribute__((ext_vector_type(4))) float floatx4;

#define EPS 1e-6f

#define RAW_BARRIER()  asm volatile("s_barrier" ::: "memory")
#define WAIT_VM4()     asm volatile("s_waitcnt vmcnt(4)" ::: "memory")
#define WAIT_VM0()     asm volatile("s_waitcnt vmcnt(0)" ::: "memory")

__device__ __forceinline__ void load_lds16(const void* g, void* l) {
    __builtin_amdgcn_global_load_lds(
        (const __attribute__((address_space(1))) void*)g,
        (__attribute__((address_space(3))) void*)l, 16, 0, 0);
}

__device__ __forceinline__ void storeOut(float* p, float v) { *p = v; }
__device__ __forceinline__ void storeOut(bf16* p, float v) { *p = __float2bfloat16(v); }

// ---------------------------------------------------------------------------
// Canonical NT GEMM: D[m][n] = sum_k A[m][k] * B[n][k]
// 128x128 block tile, BK=32, 3-stage LDS ring, ONE barrier per k-iter:
//   iter kt: wait vmcnt(4)  -> stage(kt) landed (issued 2 iters ago)
//            s_barrier      -> all waves' stage(kt) writes visible
//            stage(kt+2)    -> buf (kt+2)%3; its last readers (iter kt-1)
//                              finished ds_reads before this barrier
//            ds_read + MFMA on buf kt%3
// 3 waves/SIMD via launch_bounds; 48 KB LDS -> 3 blocks/CU.
// 1-D grid, XCD-aware decode. QKV: n0>=1024 -> transposed store into vout.
// ---------------------------------------------------------------------------
template <int BIAS_MODE, int SCALE_EN, int RESID_EN, int EXP_MODE, int ROWDIV,
          int QKV, typename OutT>
__global__ __launch_bounds__(256, 3) void gemm_nt(
    const bf16* __restrict__ A, long long aStride, int lda,
    const bf16* __restrict__ B, long long bStride, int ldb,
    OutT* __restrict__ D, long long dStride, int ldd,
    bf16* __restrict__ vout, long long vStride,
    const float* __restrict__ bias,
    const float* __restrict__ resid, long long rStride, int ldr,
    float* __restrict__ rowsum, int rsStride,
    int K, float scale, int tpb, int gx)
{
    __shared__ bf16 As[3][128 * 32];   // 3 x 8 KB
    __shared__ bf16 Bs[3][128 * 32];   // 3 x 8 KB

    const unsigned chunk = gridDim.x >> 3;
    const unsigned glob  = (blockIdx.x & 7) * chunk + (blockIdx.x >> 3);
    const unsigned z  = glob / (unsigned)tpb;
    const unsigned t  = glob % (unsigned)tpb;
    const int m0 = (int)(t / (unsigned)gx) << 7;
    const int n0 = (int)(t % (unsigned)gx) << 7;

    const int tid  = threadIdx.x;
    const int lane = tid & 63;
    const int wave = tid >> 6;
    const int wm   = wave >> 1;
    const int wn   = wave & 1;

    const bf16* Ab = A + (size_t)z * aStride + (size_t)m0 * lda;
    const bf16* Bb = B + (size_t)z * bStride + (size_t)n0 * ldb;

    floatx4 acc[4][4];
#pragma unroll
    for (int i = 0; i < 4; ++i)
#pragma unroll
        for (int j = 0; j < 4; ++j) acc[i][j] = (floatx4){0.f, 0.f, 0.f, 0.f};

    const int laneRow = lane & 15;
    const int laneKq  = lane >> 4;
    const int r1 = tid & 127, q1 = tid >> 7;   // kq 0..1
    const int i2 = tid + 256,  q2 = q1 + 2;    // kq 2..3

    auto stage = [&](int kt) {
        const int k0 = kt << 5;
        const int b  = kt % 3;
        char* Ad = (char*)As[b];
        char* Bd = (char*)Bs[b];
        load_lds16(Ab + (size_t)r1 * lda + k0 + q1 * 8, Ad + tid * 16);
        load_lds16(Ab + (size_t)r1 * lda + k0 + q2 * 8, Ad + i2 * 16);
        load_lds16(Bb + (size_t)r1 * ldb + k0 + q1 * 8, Bd + tid * 16);
        load_lds16(Bb + (size_t)r1 * ldb + k0 + q2 * 8, Bd + i2 * 16);
    };

    const int fragOff = (laneKq * 128 + laneRow) * 16;
    const int kIters = K >> 5;

    stage(0);
    stage(1);
    for (int kt = 0; kt < kIters; ++kt) {
        if (kt + 1 < kIters) { WAIT_VM4(); } else { WAIT_VM0(); }
        RAW_BARRIER();
        if (kt + 2 < kIters) stage(kt + 2);

        const int b = kt % 3;
        const char* AsB = (const char*)As[b];
        const char* BsB = (const char*)Bs[b];
        bf16x8 af[4], bfr[4];
#pragma unroll
        for (int im = 0; im < 4; ++im)
            af[im] = *(const bf16x8*)(AsB + fragOff + (wm * 64 + im * 16) * 16);
#pragma unroll
        for (int in = 0; in < 4; ++in)
            bfr[in] = *(const bf16x8*)(BsB + fragOff + (wn * 64 + in * 16) * 16);
#pragma unroll
        for (int im = 0; im < 4; ++im)
#pragma unroll
            for (int in = 0; in < 4; ++in)
                acc[im][in] = __builtin_amdgcn_mfma_f32_16x16x32_bf16(
                    af[im], bfr[in], acc[im][in], 0, 0, 0);
    }

    // Epilogue. C/D frag layout: col = lane&15, row = (lane>>4)*4 + reg
    const size_t dbase = (size_t)z * dStride;
#pragma unroll
    for (int im = 0; im < 4; ++im) {
        const int gmb = m0 + wm * 64 + im * 16 + (laneKq << 2);
        float ri[4];
        if (ROWDIV) {
#pragma unroll
            for (int r = 0; r < 4; ++r)
                ri[r] = 1.f / rowsum[(size_t)z * rsStride + gmb + r];
        }
        float rsum[4] = {0.f, 0.f, 0.f, 0.f};
#pragma unroll
        for (int in = 0; in < 4; ++in) {
            const int gn = n0 + wn * 64 + in * 16 + laneRow;
            float bn = 0.f;
            if (BIAS_MODE == 2) bn = bias[gn];
            if (QKV && n0 >= 1024) {
                union { bf16 h[4]; ushort4 u; } pk;
#pragma unroll
                for (int r = 0; r < 4; ++r)
                    pk.h[r] = __float2bfloat16(acc[im][in][r] + bn);
                *(ushort4*)(vout + (size_t)z * vStride +
                            (size_t)(gn - 1024) * 1024 + gmb) = pk.u;
            } else {
#pragma unroll
                for (int r = 0; r < 4; ++r) {
                    const int gm = gmb + r;
                    float v = acc[im][in][r];
                    if (SCALE_EN) v *= scale;
                    if (EXP_MODE) { v = __expf(v); rsum[r] += v; }
                    if (ROWDIV) v *= ri[r];
                    if (BIAS_MODE == 1) v += bias[gm];
                    if (BIAS_MODE == 2) v += bn;
                    if (RESID_EN)
                        v += resid[(size_t)z * rStride + (size_t)gm * ldr + gn];
                    storeOut(D + dbase + (size_t)gm * ldd + gn, v);
                }
            }
        }
        if (EXP_MODE) {
#pragma unroll
            for (int r = 0; r < 4; ++r) {
                float s = rsum[r];
                s += __shfl_xor(s, 1);
                s += __shfl_xor(s, 2);
                s += __shfl_xor(s, 4);
                s += __shfl_xor(s, 8);
                if (laneRow == 0)
                    atomicAdd(rowsum + (size_t)z * rsStride + gmb + r, s);
            }
        }
    }
}

// ---------------------------------------------------------------------------
// GN apply + transpose: x (B,512,1024) fp32 -> xnT (B,1024,512) bf16
// ---------------------------------------------------------------------------
__global__ __launch_bounds__(256) void gn_apply_t(const float* __restrict__ x,
                                                  const float* __restrict__ stats,
                                                  const float* __restrict__ gamma,
                                                  const float* __restrict__ beta,
                                                  bf16* __restrict__ xnT)
{
    __shared__ bf16 tile[32][36];
    const int b = blockIdx.z, c0 = blockIdx.y * 32, i0 = blockIdx.x * 32;
    {
        const int cc = threadIdx.x >> 3;
        const int i4 = (threadIdx.x & 7) << 2;
        const int c  = c0 + cc;
        const float mean = stats[2 * ((b << 5) + (c >> 4))];
        const float rstd = stats[2 * ((b << 5) + (c >> 4)) + 1];
        const float a  = gamma[c] * rstd;
        const float bb = beta[c] - mean * a;
        float4 v = *(const float4*)(x + (((size_t)(b * 512 + c)) << 10) + i0 + i4);
        tile[cc][i4 + 0] = __float2bfloat16(v.x * a + bb);
        tile[cc][i4 + 1] = __float2bfloat16(v.y * a + bb);
        tile[cc][i4 + 2] = __float2bfloat16(v.z * a + bb);
        tile[cc][i4 + 3] = __float2bfloat16(v.w * a + bb);
    }
    __syncthreads();
    {
        const int ii = threadIdx.x >> 3;
        const int c4 = (threadIdx.x & 7) << 2;
        union { bf16 h[4]; uint2 u; } pk;
        pk.h[0] = tile[c4 + 0][ii];
        pk.h[1] = tile[c4 + 1][ii];
        pk.h[2] = tile[c4 + 2][ii];
        pk.h[3] = tile[c4 + 3][ii];
        *((uint2*)(xnT + (((size_t)(b * 1024 + i0 + ii)) << 9) + c0 + c4)) = pk.u;
    }
}

// ---------------------------------------------------------------------------
// prep: weights fp32->bf16 (blocks 0..1023), qkv bias concat (1024),
// rowsum zero (1025), GroupNorm stats (1026..1537: one block per (b,g)).
// ---------------------------------------------------------------------------
__global__ __launch_bounds__(256) void prep(
    const float* __restrict__ wq, const float* __restrict__ wk,
    const float* __restrict__ wv, const float* __restrict__ wp,
    bf16* __restrict__ wqkvb, bf16* __restrict__ wpb,
    const float* __restrict__ bq, const float* __restrict__ bk,
    const float* __restrict__ bv, float* __restrict__ bqkv,
    float* __restrict__ rowsum,
    const float* __restrict__ x, float* __restrict__ stats)
{
    const int id = blockIdx.x;
    if (id < 1024) {
        const int w = id >> 8;
        const float* src = (w == 0) ? wq : (w == 1) ? wk : (w == 2) ? wv : wp;
        bf16* dst = (w < 3) ? (wqkvb + (size_t)w * 262144) : wpb;
        const int g = (id & 255) * 256 + threadIdx.x;
        float4 v = ((const float4*)src)[g];
        union { bf16 h[4]; uint2 u; } pk;
        pk.h[0] = __float2bfloat16(v.x);
        pk.h[1] = __float2bfloat16(v.y);
        pk.h[2] = __float2bfloat16(v.z);
        pk.h[3] = __float2bfloat16(v.w);
        ((uint2*)dst)[g] = pk.u;
    } else if (id == 1024) {
        for (int t = threadIdx.x; t < 1536; t += 256)
            bqkv[t] = (t < 512) ? bq[t] : (t < 1024) ? bk[t - 512] : bv[t - 1024];
    } else if (id == 1025) {
        float4 zero = {0.f, 0.f, 0.f, 0.f};
#pragma unroll
        for (int j = 0; j < 16; ++j)
            ((float4*)rowsum)[threadIdx.x + j * 256] = zero;
    } else {
        const int bg = id - 1026;
        const float4* p = (const float4*)(x + (size_t)bg * 16384);
        float s = 0.f, ss = 0.f;
        for (int i = threadIdx.x; i < 4096; i += 256) {
            float4 v = p[i];
            s  += v.x + v.y + v.z + v.w;
            ss += v.x * v.x + v.y * v.y + v.z * v.z + v.w * v.w;
        }
#pragma unroll
        for (int o = 32; o; o >>= 1) {
            s  += __shfl_down(s, o);
            ss += __shfl_down(ss, o);
        }
        __shared__ float rs[4], rss[4];
        const int wv_ = threadIdx.x >> 6;
        if ((threadIdx.x & 63) == 0) { rs[wv_] = s; rss[wv_] = ss; }
        __syncthreads();
        if (threadIdx.x == 0) {
            float S  = rs[0] + rs[1] + rs[2] + rs[3];
            float SS = rss[0] + rss[1] + rss[2] + rss[3];
            float mean = S * (1.f / 16384.f);
            float var  = SS * (1.f / 16384.f) - mean * mean;
            stats[2 * bg]     = mean;
            stats[2 * bg + 1] = rsqrtf(var + EPS);
        }
    }
}

// ---------------------------------------------------------------------------
extern "C" void kernel_launch(void* const* d_in, const int* in_sizes, int n_in,
                              void* d_out, int out_size, void* d_ws, size_t ws_size,
                              hipStream_t stream)
{
    const float* x     = (const float*)d_in[0];
    const float* gamma = (const float*)d_in[1];
    const float* beta  = (const float*)d_in[2];
    const float* wq    = (const float*)d_in[3];
    const float* bq    = (const float*)d_in[4];
    const float* wk    = (const float*)d_in[5];
    const float* bk    = (const float*)d_in[6];
    const float* wv    = (const float*)d_in[7];
    const float* bv    = (const float*)d_in[8];
    const float* wp    = (const float*)d_in[9];
    const float* bp    = (const float*)d_in[10];
    float* out = (float*)d_out;

    char* ws = (char*)d_ws;
    size_t off = 0;
    auto alloc = [&](size_t bytes) -> char* {
        char* p = ws + off;
        off += (bytes + 255) & ~(size_t)255;
        return p;
    };

    const long long S  = 1024, C = 512;
    const long long BS = S * C;
    const long long ES = S * S;

    float* stats  = (float*)alloc(512 * 2 * sizeof(float));
    float* bqkv   = (float*)alloc(1536 * sizeof(float));
    float* rowsum = (float*)alloc((size_t)16 * S * sizeof(float));
    bf16* wqkvb = (bf16*)alloc((size_t)3 * C * C * 2);  // [wq; wk; wv]
    bf16* wpb   = (bf16*)alloc((size_t)C * C * 2);
    bf16* xnT   = (bf16*)alloc((size_t)16 * BS * 2);
    bf16* qkT   = (bf16*)alloc((size_t)16 * ES * 2);    // (B,1024,1024): [qT|kT]
    bf16* vv    = (bf16*)alloc((size_t)16 * BS * 2);    // (B,512,1024)
    bf16* O2    = (bf16*)alloc((size_t)16 * BS * 2);

    int CB = 16;
    while (CB > 1 && off + (size_t)CB * ES * 2 + 1024 > ws_size) CB >>= 1;
    bf16* P = (bf16*)alloc((size_t)CB * ES * 2);

    prep<<<1538, 256, 0, stream>>>(wq, wk, wv, wp, wqkvb, wpb, bq, bk, bv,
                                   bqkv, rowsum, x, stats);

    gn_apply_t<<<dim3(32, 16, 16), 256, 0, stream>>>(x, stats, gamma, beta, xnT);

    // QKV proj: M=1024 (i), N=1536 ([q|k|v]), K=512, Z=16.
    gemm_nt<2, 0, 0, 0, 0, 1, bf16><<<1536, 256, 0, stream>>>(
        xnT, BS, 512, wqkvb, 0, 512, qkT, ES, 1024, vv, BS,
        bqkv, nullptr, 0, 0, nullptr, 0, 512, 1.f, /*tpb*/96, /*gx*/12);

    const float scale = 0.044194173824159216f; // 512^-0.5
    for (int b0 = 0; b0 < 16; b0 += CB) {
        // P[i][j] = exp(scale * q_i.k_j); rowsum[i] += (atomics)
        gemm_nt<0, 1, 0, 1, 0, 0, bf16><<<CB * 64, 256, 0, stream>>>(
            qkT + (size_t)b0 * ES, ES, 1024,
            qkT + (size_t)b0 * ES + 512, ES, 1024,
            P, ES, 1024, nullptr, 0,
            nullptr, nullptr, 0, 0, rowsum + (size_t)b0 * S, (int)S,
            512, scale, /*tpb*/64, /*gx*/8);
        // O2[i][c] = (sum_j P[i][j] vv[c][j]) / rowsum[i]
        gemm_nt<0, 0, 0, 0, 1, 0, bf16><<<CB * 32, 256, 0, stream>>>(
            P, ES, 1024,
            vv + (size_t)b0 * BS, BS, 1024,
            O2 + (size_t)b0 * BS, BS, 512, nullptr, 0,
            nullptr, nullptr, 0, 0, rowsum + (size_t)b0 * S, (int)S,
            1024, 1.f, /*tpb*/32, /*gx*/4);
    }

    // out[o][i] = sum_c wp[o][c] O2[i][c] + bp[o] + x[o][i]
    gemm_nt<1, 0, 1, 0, 0, 0, float><<<512, 256, 0, stream>>>(
        wpb, 0, 512, O2, BS, 512, out, BS, 1024, nullptr, 0,
        bp, x, BS, 1024, nullptr, 0, 512, 1.f, /*tpb*/32, /*gx*/8);
}